// Round 2
// 680.086 us; speedup vs baseline: 1.0099x; 1.0099x over previous
//
#include <hip/hip_runtime.h>

// out[b,k,p] = bias[k] + sum_{c in group k} w[c] * in[b,c,p]
// B=8, C=64, K=12, P=512*512. Pure streaming, memory-bound:
// 537 MB read + 101 MB write = 638 MB -> ~101 us floor at 6.3 TB/s.
//
// v3: split-K grid. One block = one (batch, group, 8KB-pixel-tile).
//  - grid 1024 -> 12288 (48 blocks/CU): enough TLP to cover ~900cy HBM latency.
//  - block-uniform switch(k) dispatches to a <C0,CNT> template body: every
//    load offset/weight index is compile-time, so all CNT*2 loads issue
//    back-to-back (one vmcnt window, no per-group serialization).
//  - traffic-neutral: each channel belongs to exactly one group.
//  - nontemporal loads/stores kept: zero reuse, don't pollute L2/L3.

#define NB 8
#define NC 64
#define NK 12
#define NPV 65536                 // float4 per (b,c) plane = 512*512/4
#define BLOCK 256
#define F4_PER_THREAD 2
#define TILE (BLOCK * F4_PER_THREAD)   // 512 float4 per block
#define TPP (NPV / TILE)               // 128 tiles per plane

typedef float v4f __attribute__((ext_vector_type(4)));

template <int C0, int CNT>
__device__ __forceinline__ void
group_body(const v4f* __restrict__ in4, v4f* __restrict__ out4,
           const float* __restrict__ w, float bk) {
    v4f v0[CNT], v1[CNT];
#pragma unroll
    for (int i = 0; i < CNT; ++i) {
        v0[i] = __builtin_nontemporal_load(&in4[(long long)(C0 + i) * NPV]);
        v1[i] = __builtin_nontemporal_load(&in4[(long long)(C0 + i) * NPV + BLOCK]);
    }
    v4f acc0 = {bk, bk, bk, bk};
    v4f acc1 = acc0;
#pragma unroll
    for (int i = 0; i < CNT; ++i) {
        const float wc = w[C0 + i];   // wave-uniform -> s_load
        acc0 += wc * v0[i];
        acc1 += wc * v1[i];
    }
    __builtin_nontemporal_store(acc0, &out4[0]);
    __builtin_nontemporal_store(acc1, &out4[BLOCK]);
}

__global__ __launch_bounds__(BLOCK) void
hier_invert_kernel(const float* __restrict__ in,
                   const float* __restrict__ w,
                   const float* __restrict__ bias,
                   float* __restrict__ out) {
    const int tid = threadIdx.x;
    int id = blockIdx.x;
    const int t = id & (TPP - 1);     // tile within plane (TPP=128)
    id >>= 7;
    const int k = id % NK;            // group   (block-uniform)
    const int b = id / NK;            // batch   (block-uniform)
    const int p = (t << 9) + tid;     // t*TILE + tid; second float4 at +BLOCK

    const v4f* __restrict__ in4 =
        (const v4f*)in + (long long)b * NC * NPV + p;
    v4f* __restrict__ out4 =
        (v4f*)out + (long long)(b * NK + k) * NPV + p;

    const float bk = bias[k];         // wave-uniform -> s_load

    // group boundaries: {0,1,4,14,20,28,38,46,52,57,59,62,64}
    switch (k) {                      // block-uniform -> s_cbranch, no divergence
        case 0:  group_body<0, 1>(in4, out4, w, bk);  break;  // nodata
        case 1:  group_body<1, 3>(in4, out4, w, bk);  break;  // water
        case 2:  group_body<4, 10>(in4, out4, w, bk); break;  // forest
        case 3:  group_body<14, 6>(in4, out4, w, bk); break;  // shrub
        case 4:  group_body<20, 8>(in4, out4, w, bk); break;  // grass
        case 5:  group_body<28, 10>(in4, out4, w, bk); break; // crop
        case 6:  group_body<38, 8>(in4, out4, w, bk); break;  // urban
        case 7:  group_body<46, 6>(in4, out4, w, bk); break;  // bare
        case 8:  group_body<52, 5>(in4, out4, w, bk); break;  // wetland
        case 9:  group_body<57, 2>(in4, out4, w, bk); break;  // snow
        case 10: group_body<59, 3>(in4, out4, w, bk); break;  // moss
        default: group_body<62, 2>(in4, out4, w, bk); break;  // cloud
    }
}

extern "C" void kernel_launch(void* const* d_in, const int* in_sizes, int n_in,
                              void* d_out, int out_size, void* d_ws, size_t ws_size,
                              hipStream_t stream) {
    const float* in   = (const float*)d_in[0];   // [8,64,512,512] fp32
    const float* w    = (const float*)d_in[1];   // [64] fp32
    const float* bias = (const float*)d_in[2];   // [12] fp32
    float* out        = (float*)d_out;           // [8,12,512,512] fp32

    const int grid = NB * NK * TPP;              // 8*12*128 = 12288
    hier_invert_kernel<<<grid, BLOCK, 0, stream>>>(in, w, bias, out);
}